// Round 10
// baseline (50.350 us; speedup 1.0000x reference)
//
#include <hip/hip_runtime.h>

// Problem constants (fixed by reference): B=8, H=32, S=64, C=4096, D=128
#define BB 8
#define HH 32
#define SS 64
#define CC 4096
#define DD 128
#define MAXU 2176   // per-batch compacted slot stride (used <= 2112)

// ---------------------------------------------------------------------------
// ws layout (units: 4-byte words) — every buffer write-before-read, no memset.
//   rowptr : 32832    (B*4104 CSR edge row pointers; [4096]=total)
//   adj    : 16384    (B*2048 dest cols, CSR order)
//   s      : 32768    (B*C f32 sqrt(1+indeg))
//   te     : 16384    (S*256 f32 temporal table)
//   inv    : 17408    (B*MAXU slot -> candidate)
//   remap  : 32768    (B*C cand -> slot, valid where used)
//   nused  : 64       (B u32)
//   Wt     : 16384    (W transposed, Wt[k*128+n] = W[n*128+k])
//   eg_c   : 2228224  (B*MAXU*D f32 compact relu(ae@W^T+b))
// ---------------------------------------------------------------------------

// Blocks 0..7: per-batch graph build (edge dedupe + CSR + used-compaction).
// Blocks 8..23: te table. Blocks 24..39: W transpose.
__global__ __launch_bounds__(1024) void build_graph(const int* __restrict__ hist,
                                                    const int* __restrict__ cur,
                                                    const float* __restrict__ W,
                                                    unsigned* __restrict__ rowptr,
                                                    unsigned* __restrict__ adj,
                                                    float* __restrict__ s,
                                                    unsigned* __restrict__ inv,
                                                    unsigned* __restrict__ remap,
                                                    unsigned* __restrict__ nused,
                                                    float* __restrict__ te,
                                                    float* __restrict__ Wt) {
    const int tid = threadIdx.x;
    if (blockIdx.x >= BB + 16) {                   // W transpose: 16 blocks
        int g = (blockIdx.x - BB - 16) * 1024 + tid;   // 16384 elems
        int k = g >> 7, n = g & 127;
        Wt[g] = W[n * 128 + k];
        return;
    }
    if (blockIdx.x >= BB) {                        // te table: 16 blocks
        int g = (blockIdx.x - BB) * 1024 + tid;    // S*256 = 16384
        int t = g >> 8, c = g & 255, k = c >> 1;
        float ang = (float)t * powf(10000.0f, -(float)k / 128.0f);
        te[g] = (c & 1) ? cosf(ang) : sinf(ang);
        return;
    }
    __shared__ unsigned table[4096];    // hash set of edge keys
    __shared__ unsigned cnt_a[4096];    // in-degree; later scatter cursors
    __shared__ unsigned cnt_b[4096];    // out-degree
    __shared__ unsigned used[4096];
    __shared__ unsigned pref[4096];
    __shared__ unsigned lkeys[2048];
    __shared__ unsigned wbase[17];
    __shared__ unsigned total;
    const int b = blockIdx.x;
    const int lane = tid & 63, wv = tid >> 6;

#pragma unroll
    for (int r = 0; r < 4; ++r) {
        int g = tid + r * 1024;
        table[g] = 0xFFFFFFFFu;
        cnt_a[g] = 0u;
        cnt_b[g] = 0u;
        used[g] = 0u;
    }
    if (tid == 0) total = 0u;
    __syncthreads();

    for (int t = tid; t < HH * SS; t += 1024) used[hist[b * HH * SS + t]] = 1u;
    if (tid < SS) used[cur[b * SS + tid]] = 1u;

    for (int t = tid; t < HH * (SS - 1); t += 1024) {   // edge dedupe
        int h = t / 63, ss = t - h * 63;
        int base = (b * HH + h) * SS + ss;
        int i = hist[base], j = hist[base + 1];
        if (i != j) {
            unsigned key = ((unsigned)i << 12) | (unsigned)j;
            unsigned hh = (key * 2654435761u) >> 20;
            for (;;) {
                hh &= 4095u;
                unsigned old = atomicCAS(&table[hh], 0xFFFFFFFFu, key);
                if (old == 0xFFFFFFFFu) {
                    unsigned slot = atomicAdd(&total, 1u);
                    lkeys[slot] = key;
                    atomicAdd(&cnt_a[key & 4095u], 1u);
                    atomicAdd(&cnt_b[key >> 12], 1u);
                    break;
                }
                if (old == key) break;
                ++hh;
            }
        }
    }
    __syncthreads();

#pragma unroll
    for (int r = 0; r < 4; ++r) {                  // s from in-degree
        int g = tid + r * 1024;
        s[b * CC + g] = sqrtf(1.0f + (float)cnt_a[g]);
    }

    // packed scan: v = (outdeg<<13)|used -> CSR rowptr + compact slot map
    {
        unsigned v0 = (cnt_b[tid * 4]     << 13) | used[tid * 4];
        unsigned v1 = (cnt_b[tid * 4 + 1] << 13) | used[tid * 4 + 1];
        unsigned v2 = (cnt_b[tid * 4 + 2] << 13) | used[tid * 4 + 2];
        unsigned v3 = (cnt_b[tid * 4 + 3] << 13) | used[tid * 4 + 3];
        unsigned tsum = v0 + v1 + v2 + v3;
        unsigned x = tsum;
#pragma unroll
        for (int off = 1; off < 64; off <<= 1) {
            unsigned y = __shfl_up(x, off);
            if (lane >= off) x += y;
        }
        if (lane == 63) wbase[wv + 1] = x;
        __syncthreads();
        if (tid == 0) {
            wbase[0] = 0u;
            for (int w = 1; w <= 16; ++w) wbase[w] += wbase[w - 1];
        }
        __syncthreads();
        unsigned texcl = wbase[wv] + x - tsum;
        pref[tid * 4]     = texcl;
        pref[tid * 4 + 1] = texcl + v0;
        pref[tid * 4 + 2] = texcl + v0 + v1;
        pref[tid * 4 + 3] = texcl + v0 + v1 + v2;
    }
#pragma unroll
    for (int r = 0; r < 4; ++r) cnt_a[tid + r * 1024] = 0u;   // scatter cursors
    __syncthreads();

#pragma unroll
    for (int r = 0; r < 4; ++r) {
        int g = tid + r * 1024;
        unsigned p = pref[g];
        rowptr[b * 4104 + g] = p >> 13;
        unsigned slot = p & 8191u;
        remap[b * CC + g] = slot;
        if (used[g]) inv[b * MAXU + slot] = (unsigned)g;
    }
    if (tid == 0) {
        rowptr[b * 4104 + 4096] = wbase[16] >> 13;
        nused[b] = wbase[16] & 8191u;
    }
    for (int e = tid; e < (int)total; e += 1024) { // adjacency scatter
        unsigned key = lkeys[e];
        unsigned i = key >> 12, j = key & 4095u;
        unsigned pos = (pref[i] >> 13) + atomicAdd(&cnt_a[i], 1u);
        adj[b * 2048 + pos] = j;
    }
}

// Merged ae+gemm (removes the 17MB ae_c HBM round-trip + one launch).
// Phase A: wave-per-row CSR gather ae = s_i*(s_i*E[i] + sum s_j*E[j]) into
// LDS As (exactly R9's ae_build decomposition: 544 blocks x 4 waves of TLP).
// Phase B: R9's gemm_eg unchanged — Ws K-split staging, As stride 131
// (GEMM row reads hit 16 distinct banks), eg_c = relu(As @ W^T + bias).
__global__ __launch_bounds__(256) void ae_gemm(const float* __restrict__ E,
                                               const float* __restrict__ s,
                                               const unsigned* __restrict__ rowptr,
                                               const unsigned* __restrict__ adj,
                                               const unsigned* __restrict__ inv,
                                               const unsigned* __restrict__ nused,
                                               const float* __restrict__ Wt,
                                               const float* __restrict__ bg,
                                               float* __restrict__ eg_c) {
    __shared__ float As[32][131];
    __shared__ float Ws[64][128];
    const int b = blockIdx.x / (MAXU / 32);                // 68 blocks per batch
    const int s0 = (blockIdx.x % (MAXU / 32)) * 32;
    const unsigned nu = nused[b];
    if ((unsigned)s0 >= nu) return;
    const int tid = threadIdx.x;
    const int lane = tid & 63, wv = tid >> 6;

    // phase A: each wave builds 8 ae rows (float2 per lane, 2-way LDS = free)
    const float2* Eb = (const float2*)(E + (size_t)b * CC * DD);
#pragma unroll
    for (int q = 0; q < 8; ++q) {
        int r = wv * 8 + q;
        int slot = s0 + r;
        float2 acc = make_float2(0.f, 0.f);
        if ((unsigned)slot < nu) {
            unsigned c = inv[b * MAXU + slot];
            float si = s[b * CC + c];
            float2 e = Eb[(size_t)c * 64 + lane];
            acc.x = si * e.x; acc.y = si * e.y;
            unsigned p0 = rowptr[b * 4104 + c], p1 = rowptr[b * 4104 + c + 1];
            for (unsigned p = p0; p < p1; ++p) {
                unsigned j = adj[b * 2048 + p];
                float sj = s[b * CC + j];
                float2 ej = Eb[(size_t)j * 64 + lane];
                acc.x += sj * ej.x;
                acc.y += sj * ej.y;
            }
            acc.x *= si; acc.y *= si;
        }
        As[r][lane * 2]     = acc.x;
        As[r][lane * 2 + 1] = acc.y;
    }

    // phase B: eg = relu(As @ W^T + bias)
    const int tr = tid >> 4, tc = tid & 15;
    float bgv[8];
#pragma unroll
    for (int c = 0; c < 8; ++c) bgv[c] = bg[tc * 8 + c];
    float acc[2][8];
#pragma unroll
    for (int r = 0; r < 2; ++r)
#pragma unroll
        for (int c = 0; c < 8; ++c) acc[r][c] = 0.f;

    for (int kk = 0; kk < 128; kk += 64) {
        __syncthreads();                           // As ready / Ws reusable
        for (int idx = tid; idx < 64 * 128; idx += 256) {   // stage W half
            int kl = idx >> 7, n = idx & 127;
            Ws[kl][n] = Wt[(kk + kl) * 128 + n];   // coalesced
        }
        __syncthreads();
#pragma unroll 4
        for (int kl = 0; kl < 64; ++kl) {
            float a0 = As[tr * 2][kk + kl];        // 16 distinct banks
            float a1 = As[tr * 2 + 1][kk + kl];
            const float4* wp = (const float4*)&Ws[kl][tc * 8];
            float4 w0 = wp[0], w1 = wp[1];
            float wvv[8] = {w0.x, w0.y, w0.z, w0.w, w1.x, w1.y, w1.z, w1.w};
#pragma unroll
            for (int c = 0; c < 8; ++c) {
                acc[0][c] = fmaf(a0, wvv[c], acc[0][c]);
                acc[1][c] = fmaf(a1, wvv[c], acc[1][c]);
            }
        }
    }

#pragma unroll
    for (int r = 0; r < 2; ++r) {
        int row = tr * 2 + r;
        if ((unsigned)(s0 + row) >= nu) continue;
        float4 o0, o1;
        o0.x = fmaxf(acc[r][0] + bgv[0], 0.f);
        o0.y = fmaxf(acc[r][1] + bgv[1], 0.f);
        o0.z = fmaxf(acc[r][2] + bgv[2], 0.f);
        o0.w = fmaxf(acc[r][3] + bgv[3], 0.f);
        o1.x = fmaxf(acc[r][4] + bgv[4], 0.f);
        o1.y = fmaxf(acc[r][5] + bgv[5], 0.f);
        o1.z = fmaxf(acc[r][6] + bgv[6], 0.f);
        o1.w = fmaxf(acc[r][7] + bgv[7], 0.f);
        float* outp = eg_c + ((size_t)b * MAXU + s0 + row) * 128 + tc * 8;
        ((float4*)outp)[0] = o0;
        ((float4*)outp)[1] = o1;
    }
}

// One wave per output row: out[row] = [eg_c[remap[cand]] | E[cand]] + te[s].
__global__ __launch_bounds__(256) void scatter_out(const int* __restrict__ hist,
                                                   const int* __restrict__ cur,
                                                   const unsigned* __restrict__ remap,
                                                   const float4* __restrict__ Egc4,
                                                   const float4* __restrict__ E4,
                                                   const float4* __restrict__ te4,
                                                   float4* __restrict__ out4) {
    int g = blockIdx.x * 256 + threadIdx.x;
    int row = g >> 6, lane = g & 63;
    int b, spos, cand;
    if (row < BB * HH * SS) {
        spos = row & 63;
        b = row >> 11;
        cand = hist[row];
    } else {
        int rc = row - BB * HH * SS;
        spos = rc & 63;
        b = rc >> 6;
        cand = cur[rc];
    }
    float4 v;
    if (lane < 32) {
        unsigned slot = remap[b * CC + cand];
        v = Egc4[((size_t)b * MAXU + slot) * 32 + lane];
    } else {
        v = E4[(size_t)(b * CC + cand) * 32 + (lane - 32)];
    }
    float4 t = te4[spos * 64 + lane];
    out4[(size_t)row * 64 + lane] = make_float4(v.x + t.x, v.y + t.y, v.z + t.z, v.w + t.w);
}

extern "C" void kernel_launch(void* const* d_in, const int* in_sizes, int n_in,
                              void* d_out, int out_size, void* d_ws, size_t ws_size,
                              hipStream_t stream) {
    const int*   hist = (const int*)d_in[1];
    const int*   cur  = (const int*)d_in[2];
    const float* E    = (const float*)d_in[3];
    const float* W    = (const float*)d_in[4];
    const float* bg   = (const float*)d_in[5];
    float* out = (float*)d_out;

    unsigned* ws_u   = (unsigned*)d_ws;
    unsigned* rowptr = ws_u;                         // 32832
    unsigned* adj    = rowptr + 32832;               // 16384
    float*    sarr   = (float*)(adj + 16384);        // 32768
    float*    te     = sarr + 32768;                 // 16384
    unsigned* inv    = (unsigned*)(te + 16384);      // 17408
    unsigned* remap  = inv + 17408;                  // 32768
    unsigned* nused  = remap + 32768;                // 64
    float*    Wt     = (float*)(nused + 64);         // 16384
    float*    eg_c   = Wt + 16384;                   // 2228224

    build_graph<<<BB + 32, 1024, 0, stream>>>(hist, cur, W, rowptr, adj, sarr,
                                              inv, remap, nused, te, Wt);
    ae_gemm<<<BB * (MAXU / 32), 256, 0, stream>>>(E, sarr, rowptr, adj, inv,
                                                  nused, Wt, bg, eg_c);
    scatter_out<<<(BB * HH * SS + BB * SS) / 4, 256, 0, stream>>>(
        hist, cur, remap, (const float4*)eg_c, (const float4*)E,
        (const float4*)te, (float4*)out);
}